// Round 1
// baseline (892.142 us; speedup 1.0000x reference)
//
#include <hip/hip_runtime.h>

#define NPIX 16384   // 128*128
#define BATCH 8

// ---------------- avg pool 2x2 stride 2: x (B,32,256,256) -> (B,32,128,128)
__global__ void avgpool_kernel(const float* __restrict__ x, float* __restrict__ out) {
    int t = blockIdx.x * blockDim.x + threadIdx.x;        // B*32*NPIX threads
    int pix = t & (NPIX - 1);
    int j = pix & 127, i = pix >> 7;
    int bc = t >> 14;                                     // b*32+m
    const float* p = x + (size_t)bc * 65536 + (size_t)(2 * i) * 256 + 2 * j;
    out[t] = 0.25f * (p[0] + p[1] + p[256] + p[257]);
}

// ---------------- kernel generation: in (B,C,128,128) -> k (B,9,128,128)
// k = conv1x1(relu(bn(conv1x1(in, w_red), eps=1e-5)), w_span)
template <int C>
__global__ void kgen_kernel(const float* __restrict__ in,
                            const float* __restrict__ w_red,   // (C,C)
                            const float* __restrict__ g,
                            const float* __restrict__ bta,
                            const float* __restrict__ mn,
                            const float* __restrict__ vr,
                            const float* __restrict__ w_span,  // (9,C)
                            float* __restrict__ kout) {
    int t = blockIdx.x * blockDim.x + threadIdx.x;        // B*NPIX threads
    int b = t >> 14;
    int pix = t & (NPIX - 1);
    float inv[C];
    const float* base = in + ((size_t)b * C) * NPIX + pix;
#pragma unroll
    for (int m = 0; m < C; ++m) inv[m] = base[(size_t)m * NPIX];
    float kacc[9];
#pragma unroll
    for (int r = 0; r < 9; ++r) kacc[r] = 0.f;
    for (int c = 0; c < C; ++c) {                         // uniform loop -> scalar weight loads
        float acc = 0.f;
#pragma unroll
        for (int m = 0; m < C; ++m) acc = fmaf(w_red[c * C + m], inv[m], acc);
        float sc = g[c] * rsqrtf(vr[c] + 1e-5f);
        float tt = (acc - mn[c]) * sc + bta[c];
        tt = tt > 0.f ? tt : 0.f;
#pragma unroll
        for (int r = 0; r < 9; ++r) kacc[r] = fmaf(w_span[r * C + c], tt, kacc[r]);
    }
    float* ko = kout + ((size_t)b * 9) * NPIX + pix;
#pragma unroll
    for (int r = 0; r < 9; ++r) ko[(size_t)r * NPIX] = kacc[r];
}

// ---------------- stage-1 involution apply on raw x (stride 2, pad 1, dil 1)
// p[b,m,i,j] = sum_k x[b,m,2i-1+ky,2j-1+kx] * k1[b,3ky+kx,i,j]
__global__ void apply1_kernel(const float* __restrict__ x, const float* __restrict__ kb,
                              float* __restrict__ p) {
    int t = blockIdx.x * blockDim.x + threadIdx.x;        // B*32*NPIX threads
    int pix = t & (NPIX - 1);
    int j = pix & 127, i = pix >> 7;
    int bm = t >> 14;
    int b = bm >> 5;
    const float* kp = kb + ((size_t)b * 9) * NPIX + pix;
    const float* xp = x + (size_t)bm * 65536;
    float acc = 0.f;
#pragma unroll
    for (int ky = 0; ky < 3; ++ky) {
        int y = 2 * i - 1 + ky;
        if ((unsigned)y < 256u) {
#pragma unroll
            for (int kx = 0; kx < 3; ++kx) {
                int xx = 2 * j - 1 + kx;
                if ((unsigned)xx < 256u)
                    acc = fmaf(xp[(size_t)y * 256 + xx], kp[(size_t)(3 * ky + kx) * NPIX], acc);
            }
        }
    }
    p[t] = acc;
}

// ---------------- 1x1 conv 32->64 + bn(1e-3) + prelu : p -> o1
__global__ void conv1_kernel(const float* __restrict__ p, const float* __restrict__ w,  // (64,32)
                             const float* __restrict__ g, const float* __restrict__ bt,
                             const float* __restrict__ mn, const float* __restrict__ vr,
                             const float* __restrict__ pr, float* __restrict__ o1) {
    int t = blockIdx.x * blockDim.x + threadIdx.x;        // B*64*NPIX threads
    int pix = t & (NPIX - 1);
    int bc = t >> 14;
    int b = bc >> 6, c = bc & 63;                         // c uniform per block
    const float* pp = p + ((size_t)b * 32) * NPIX + pix;
    float acc = 0.f;
#pragma unroll
    for (int m = 0; m < 32; ++m) acc = fmaf(w[c * 32 + m], pp[(size_t)m * NPIX], acc);
    float sc = g[c] * rsqrtf(vr[c] + 1e-3f);
    float v = (acc - mn[c]) * sc + bt[c];
    v = v > 0.f ? v : pr[c] * v;
    o1[t] = v;
}

// ---------------- dilated involution apply + bn_d + prelu_d + bn_f + prelu_f -> out slice
__global__ void apply_dil_kernel(const float* __restrict__ o1, const float* __restrict__ kb,
                                 int dil,
                                 const float* __restrict__ gd, const float* __restrict__ bd,
                                 const float* __restrict__ md, const float* __restrict__ vd,
                                 const float* __restrict__ ad,
                                 const float* __restrict__ gf, const float* __restrict__ bf,
                                 const float* __restrict__ mf, const float* __restrict__ vf,
                                 const float* __restrict__ af,
                                 float* __restrict__ out, int co_base) {
    int t = blockIdx.x * blockDim.x + threadIdx.x;        // B*64*NPIX threads
    int pix = t & (NPIX - 1);
    int j = pix & 127, i = pix >> 7;
    int bc = t >> 14;
    int b = bc >> 6, c = bc & 63;
    const float* kp = kb + ((size_t)b * 9) * NPIX + pix;
    const float* xp = o1 + (size_t)bc * NPIX;
    float acc = 0.f;
#pragma unroll
    for (int ky = 0; ky < 3; ++ky) {
        int y = i + dil * (ky - 1);
        if ((unsigned)y < 128u) {
#pragma unroll
            for (int kx = 0; kx < 3; ++kx) {
                int xx = j + dil * (kx - 1);
                if ((unsigned)xx < 128u)
                    acc = fmaf(xp[(size_t)y * 128 + xx], kp[(size_t)(3 * ky + kx) * NPIX], acc);
            }
        }
    }
    float sc = gd[c] * rsqrtf(vd[c] + 1e-3f);
    float v = (acc - md[c]) * sc + bd[c];
    v = v > 0.f ? v : ad[c] * v;
    int cf = co_base + c;
    float sf = gf[cf] * rsqrtf(vf[cf] + 1e-3f);
    v = (v - mf[cf]) * sf + bf[cf];
    v = v > 0.f ? v : af[cf] * v;
    out[((size_t)(b * 320 + cf)) * NPIX + pix] = v;
}

extern "C" void kernel_launch(void* const* d_in, const int* in_sizes, int n_in,
                              void* d_out, int out_size, void* d_ws, size_t ws_size,
                              hipStream_t stream) {
    const float* x       = (const float*)d_in[0];
    const float* w1_init = (const float*)d_in[1];
    const float* w1_red  = (const float*)d_in[2];
    const float* s1_g    = (const float*)d_in[3];
    const float* s1_b    = (const float*)d_in[4];
    const float* s1_m    = (const float*)d_in[5];
    const float* s1_v    = (const float*)d_in[6];
    const float* w1_span = (const float*)d_in[7];
    const float* bn1_g   = (const float*)d_in[8];
    const float* bn1_b   = (const float*)d_in[9];
    const float* bn1_m   = (const float*)d_in[10];
    const float* bn1_v   = (const float*)d_in[11];
    const float* pr1     = (const float*)d_in[12];
    const float* wd_red  = (const float*)d_in[13];  // (5,64,64)
    const float* sd_g    = (const float*)d_in[14];
    const float* sd_b    = (const float*)d_in[15];
    const float* sd_m    = (const float*)d_in[16];
    const float* sd_v    = (const float*)d_in[17];
    const float* wd_span = (const float*)d_in[18];  // (5,9,64)
    const float* bnd_g   = (const float*)d_in[19];
    const float* bnd_b   = (const float*)d_in[20];
    const float* bnd_m   = (const float*)d_in[21];
    const float* bnd_v   = (const float*)d_in[22];
    const float* prd     = (const float*)d_in[23];
    const float* bnf_g   = (const float*)d_in[24];
    const float* bnf_b   = (const float*)d_in[25];
    const float* bnf_m   = (const float*)d_in[26];
    const float* bnf_v   = (const float*)d_in[27];
    const float* prf     = (const float*)d_in[28];
    float* out = (float*)d_out;

    float* ws    = (float*)d_ws;
    float* o1buf = ws;                        // 8*64*16384 = 8388608 floats
    float* kbuf  = ws + 8388608;              // 8*9*16384  = 1179648 floats
    float* tbuf  = ws + 8388608 + 1179648;    // 8*32*16384 = 4194304 floats (pooled, then p)

    const int TB = 256;
    const int dils[5] = {1, 2, 4, 8, 16};

    // stage 1
    hipLaunchKernelGGL(avgpool_kernel, dim3(BATCH * 32 * NPIX / TB), dim3(TB), 0, stream, x, tbuf);
    hipLaunchKernelGGL((kgen_kernel<32>), dim3(BATCH * NPIX / TB), dim3(TB), 0, stream,
                       tbuf, w1_red, s1_g, s1_b, s1_m, s1_v, w1_span, kbuf);
    hipLaunchKernelGGL(apply1_kernel, dim3(BATCH * 32 * NPIX / TB), dim3(TB), 0, stream, x, kbuf, tbuf);
    hipLaunchKernelGGL(conv1_kernel, dim3(BATCH * 64 * NPIX / TB), dim3(TB), 0, stream,
                       tbuf, w1_init, bn1_g, bn1_b, bn1_m, bn1_v, pr1, o1buf);

    // dilated stages
    for (int s = 0; s < 5; ++s) {
        hipLaunchKernelGGL((kgen_kernel<64>), dim3(BATCH * NPIX / TB), dim3(TB), 0, stream,
                           o1buf, wd_red + s * 64 * 64, sd_g + s * 64, sd_b + s * 64,
                           sd_m + s * 64, sd_v + s * 64, wd_span + s * 9 * 64, kbuf);
        hipLaunchKernelGGL(apply_dil_kernel, dim3(BATCH * 64 * NPIX / TB), dim3(TB), 0, stream,
                           o1buf, kbuf, dils[s],
                           bnd_g + s * 64, bnd_b + s * 64, bnd_m + s * 64, bnd_v + s * 64, prd + s * 64,
                           bnf_g, bnf_b, bnf_m, bnf_v, prf,
                           out, s * 64);
    }
}

// Round 2
// 770.528 us; speedup vs baseline: 1.1578x; 1.1578x over previous
//
#include <hip/hip_runtime.h>

#define NPIX 16384   // 128*128
#define BATCH 8

// ---------------- stage-1 kernel generation with fused 2x2 avg-pool
// x (B,32,256,256) -> k1 (B,9,128,128)
__global__ void kgen1_kernel(const float* __restrict__ x,
                             const float* __restrict__ w_red,   // (32,32)
                             const float* __restrict__ g,
                             const float* __restrict__ bta,
                             const float* __restrict__ mn,
                             const float* __restrict__ vr,
                             const float* __restrict__ w_span,  // (9,32)
                             float* __restrict__ kout) {
    int t = blockIdx.x * blockDim.x + threadIdx.x;        // B*NPIX threads
    int b = t >> 14;
    int pix = t & (NPIX - 1);
    int j = pix & 127, i = pix >> 7;
    float inv[32];
    const float* xb = x + ((size_t)b * 32) * 65536 + (size_t)(2 * i) * 256 + 2 * j;
#pragma unroll
    for (int m = 0; m < 32; ++m) {
        const float2* r0 = (const float2*)(xb + (size_t)m * 65536);
        const float2* r1 = (const float2*)(xb + (size_t)m * 65536 + 256);
        float2 a = r0[0], bb = r1[0];
        inv[m] = 0.25f * ((a.x + a.y) + (bb.x + bb.y));
    }
    float kacc[9];
#pragma unroll
    for (int r = 0; r < 9; ++r) kacc[r] = 0.f;
    for (int c = 0; c < 32; ++c) {
        float a0 = 0.f, a1 = 0.f, a2 = 0.f, a3 = 0.f;
#pragma unroll
        for (int m = 0; m < 32; m += 4) {
            a0 = fmaf(w_red[c * 32 + m + 0], inv[m + 0], a0);
            a1 = fmaf(w_red[c * 32 + m + 1], inv[m + 1], a1);
            a2 = fmaf(w_red[c * 32 + m + 2], inv[m + 2], a2);
            a3 = fmaf(w_red[c * 32 + m + 3], inv[m + 3], a3);
        }
        float acc = (a0 + a1) + (a2 + a3);
        float sc = g[c] * rsqrtf(vr[c] + 1e-5f);
        float tt = (acc - mn[c]) * sc + bta[c];
        tt = tt > 0.f ? tt : 0.f;
#pragma unroll
        for (int r = 0; r < 9; ++r) kacc[r] = fmaf(w_span[r * 32 + c], tt, kacc[r]);
    }
    float* ko = kout + ((size_t)b * 9) * NPIX + pix;
#pragma unroll
    for (int r = 0; r < 9; ++r) ko[(size_t)r * NPIX] = kacc[r];
}

// ---------------- stage-1 involution apply on raw x (stride 2, pad 1, dil 1)
// XCD-swizzled: each XCD sweeps all 32 channels over a fixed pixel slab.
__global__ void apply1_kernel(const float* __restrict__ x, const float* __restrict__ kb,
                              float* __restrict__ p) {
    int gblk = blockIdx.x;                                // 8b * 8pth * 32m * 8ptl
    int ptl = gblk & 7; int q = gblk >> 3;
    int m = q & 31; int q2 = q >> 5;                      // q2 = b*8 + pth
    int pth = q2 & 7; int b = q2 >> 3;
    int pix = (pth * 8 + ptl) * 256 + threadIdx.x;
    int j = pix & 127, i = pix >> 7;
    const float* kp = kb + ((size_t)b * 9) * NPIX + pix;
    const float* xp = x + ((size_t)(b * 32 + m)) * 65536;
    float acc = 0.f;
#pragma unroll
    for (int ky = 0; ky < 3; ++ky) {
        int y = 2 * i - 1 + ky;
        if ((unsigned)y < 256u) {
#pragma unroll
            for (int kx = 0; kx < 3; ++kx) {
                int xx = 2 * j - 1 + kx;
                if ((unsigned)xx < 256u)
                    acc = fmaf(xp[(size_t)y * 256 + xx], kp[(size_t)(3 * ky + kx) * NPIX], acc);
            }
        }
    }
    p[((size_t)(b * 32 + m)) * NPIX + pix] = acc;
}

// ---------------- 1x1 conv 32->64 + bn(1e-3) + prelu : p -> o1 (XCD-swizzled)
__global__ void conv1_kernel(const float* __restrict__ p, const float* __restrict__ w,  // (64,32)
                             const float* __restrict__ g, const float* __restrict__ bt,
                             const float* __restrict__ mn, const float* __restrict__ vr,
                             const float* __restrict__ pr, float* __restrict__ o1) {
    int gblk = blockIdx.x;                                // 8b * 8pth * 64c * 8ptl
    int ptl = gblk & 7; int q = gblk >> 3;
    int c = q & 63; int q2 = q >> 6;
    int pth = q2 & 7; int b = q2 >> 3;
    int pix = (pth * 8 + ptl) * 256 + threadIdx.x;
    const float* pp = p + ((size_t)b * 32) * NPIX + pix;
    float a0 = 0.f, a1 = 0.f, a2 = 0.f, a3 = 0.f;
#pragma unroll
    for (int m = 0; m < 32; m += 4) {
        a0 = fmaf(w[c * 32 + m + 0], pp[(size_t)(m + 0) * NPIX], a0);
        a1 = fmaf(w[c * 32 + m + 1], pp[(size_t)(m + 1) * NPIX], a1);
        a2 = fmaf(w[c * 32 + m + 2], pp[(size_t)(m + 2) * NPIX], a2);
        a3 = fmaf(w[c * 32 + m + 3], pp[(size_t)(m + 3) * NPIX], a3);
    }
    float acc = (a0 + a1) + (a2 + a3);
    float sc = g[c] * rsqrtf(vr[c] + 1e-3f);
    float v = (acc - mn[c]) * sc + bt[c];
    v = v > 0.f ? v : pr[c] * v;
    o1[((size_t)(b * 64 + c)) * NPIX + pix] = v;
}

// ---------------- fused kernel-gen for all 5 dilated stages
// o1 (B,64,128,128) -> k5 (5,B,9,128,128)
__global__ void kgen5_kernel(const float* __restrict__ o1,
                             const float* __restrict__ wred5,   // (5,64,64)
                             const float* __restrict__ sg5, const float* __restrict__ sb5,
                             const float* __restrict__ sm5, const float* __restrict__ sv5,
                             const float* __restrict__ wspan5,  // (5,9,64)
                             float* __restrict__ kout) {
    int t = blockIdx.x * blockDim.x + threadIdx.x;        // B*NPIX threads
    int b = t >> 14;
    int pix = t & (NPIX - 1);
    float inv[64];
    const float* base = o1 + ((size_t)b * 64) * NPIX + pix;
#pragma unroll
    for (int m = 0; m < 64; ++m) inv[m] = base[(size_t)m * NPIX];
    for (int s = 0; s < 5; ++s) {
        const float* wr = wred5 + s * 4096;
        const float* wsp = wspan5 + s * 576;
        const float* g = sg5 + s * 64;  const float* bt = sb5 + s * 64;
        const float* mn = sm5 + s * 64; const float* vr = sv5 + s * 64;
        float kacc[9];
#pragma unroll
        for (int r = 0; r < 9; ++r) kacc[r] = 0.f;
        for (int c = 0; c < 64; ++c) {
            float a0 = 0.f, a1 = 0.f, a2 = 0.f, a3 = 0.f;
#pragma unroll
            for (int m = 0; m < 64; m += 4) {
                a0 = fmaf(wr[c * 64 + m + 0], inv[m + 0], a0);
                a1 = fmaf(wr[c * 64 + m + 1], inv[m + 1], a1);
                a2 = fmaf(wr[c * 64 + m + 2], inv[m + 2], a2);
                a3 = fmaf(wr[c * 64 + m + 3], inv[m + 3], a3);
            }
            float acc = (a0 + a1) + (a2 + a3);
            float sc = g[c] * rsqrtf(vr[c] + 1e-5f);
            float tt = (acc - mn[c]) * sc + bt[c];
            tt = tt > 0.f ? tt : 0.f;
#pragma unroll
            for (int r = 0; r < 9; ++r) kacc[r] = fmaf(wsp[r * 64 + c], tt, kacc[r]);
        }
        float* ko = kout + ((size_t)(s * BATCH + b) * 9) * NPIX + pix;
#pragma unroll
        for (int r = 0; r < 9; ++r) ko[(size_t)r * NPIX] = kacc[r];
    }
}

// ---------------- fused dilated involution apply for all 5 stages (XCD-swizzled)
__global__ void apply5_kernel(const float* __restrict__ o1, const float* __restrict__ kb, // (5,B,9,NPIX)
                              const float* __restrict__ gd5, const float* __restrict__ bd5,
                              const float* __restrict__ md5, const float* __restrict__ vd5,
                              const float* __restrict__ ad5,
                              const float* __restrict__ gf, const float* __restrict__ bf,
                              const float* __restrict__ mf, const float* __restrict__ vf,
                              const float* __restrict__ af,
                              float* __restrict__ out) {
    int gblk = blockIdx.x;                                // 8b * 8pth * 64c * 8ptl
    int ptl = gblk & 7; int q = gblk >> 3;
    int c = q & 63; int q2 = q >> 6;
    int pth = q2 & 7; int b = q2 >> 3;
    int pix = (pth * 8 + ptl) * 256 + threadIdx.x;
    int j = pix & 127, i = pix >> 7;
    const float* xp = o1 + ((size_t)(b * 64 + c)) * NPIX;
    float center = xp[pix];
    const int dils[5] = {1, 2, 4, 8, 16};
#pragma unroll
    for (int s = 0; s < 5; ++s) {
        int dil = dils[s];
        const float* kp = kb + ((size_t)(s * BATCH + b) * 9) * NPIX + pix;
        float acc = 0.f;
#pragma unroll
        for (int ky = 0; ky < 3; ++ky) {
            int y = i + dil * (ky - 1);
            if ((unsigned)y < 128u) {
#pragma unroll
                for (int kx = 0; kx < 3; ++kx) {
                    int xx = j + dil * (kx - 1);
                    if ((unsigned)xx < 128u) {
                        float xv = (ky == 1 && kx == 1) ? center : xp[(size_t)y * 128 + xx];
                        acc = fmaf(xv, kp[(size_t)(3 * ky + kx) * NPIX], acc);
                    }
                }
            }
        }
        int sc64 = s * 64 + c;
        float scd = gd5[sc64] * rsqrtf(vd5[sc64] + 1e-3f);
        float v = (acc - md5[sc64]) * scd + bd5[sc64];
        v = v > 0.f ? v : ad5[sc64] * v;
        float scf = gf[sc64] * rsqrtf(vf[sc64] + 1e-3f);
        v = (v - mf[sc64]) * scf + bf[sc64];
        v = v > 0.f ? v : af[sc64] * v;
        out[((size_t)(b * 320 + sc64)) * NPIX + pix] = v;
    }
}

extern "C" void kernel_launch(void* const* d_in, const int* in_sizes, int n_in,
                              void* d_out, int out_size, void* d_ws, size_t ws_size,
                              hipStream_t stream) {
    const float* x       = (const float*)d_in[0];
    const float* w1_init = (const float*)d_in[1];
    const float* w1_red  = (const float*)d_in[2];
    const float* s1_g    = (const float*)d_in[3];
    const float* s1_b    = (const float*)d_in[4];
    const float* s1_m    = (const float*)d_in[5];
    const float* s1_v    = (const float*)d_in[6];
    const float* w1_span = (const float*)d_in[7];
    const float* bn1_g   = (const float*)d_in[8];
    const float* bn1_b   = (const float*)d_in[9];
    const float* bn1_m   = (const float*)d_in[10];
    const float* bn1_v   = (const float*)d_in[11];
    const float* pr1     = (const float*)d_in[12];
    const float* wd_red  = (const float*)d_in[13];  // (5,64,64)
    const float* sd_g    = (const float*)d_in[14];
    const float* sd_b    = (const float*)d_in[15];
    const float* sd_m    = (const float*)d_in[16];
    const float* sd_v    = (const float*)d_in[17];
    const float* wd_span = (const float*)d_in[18];  // (5,9,64)
    const float* bnd_g   = (const float*)d_in[19];
    const float* bnd_b   = (const float*)d_in[20];
    const float* bnd_m   = (const float*)d_in[21];
    const float* bnd_v   = (const float*)d_in[22];
    const float* prd     = (const float*)d_in[23];
    const float* bnf_g   = (const float*)d_in[24];
    const float* bnf_b   = (const float*)d_in[25];
    const float* bnf_m   = (const float*)d_in[26];
    const float* bnf_v   = (const float*)d_in[27];
    const float* prf     = (const float*)d_in[28];
    float* out = (float*)d_out;

    float* ws    = (float*)d_ws;
    float* o1buf = ws;                         // 8*64*16384  = 8388608 floats
    float* k1buf = ws + 8388608;               // 8*9*16384   = 1179648 floats
    float* k5buf = ws + 8388608 + 1179648;     // 5*8*9*16384 = 5898240 floats
    float* pbuf  = ws + 8388608 + 1179648 + 5898240;  // 8*32*16384 = 4194304 floats

    const int TB = 256;

    hipLaunchKernelGGL(kgen1_kernel, dim3(BATCH * NPIX / TB), dim3(TB), 0, stream,
                       x, w1_red, s1_g, s1_b, s1_m, s1_v, w1_span, k1buf);
    hipLaunchKernelGGL(apply1_kernel, dim3(BATCH * 32 * NPIX / TB), dim3(TB), 0, stream,
                       x, k1buf, pbuf);
    hipLaunchKernelGGL(conv1_kernel, dim3(BATCH * 64 * NPIX / TB), dim3(TB), 0, stream,
                       pbuf, w1_init, bn1_g, bn1_b, bn1_m, bn1_v, pr1, o1buf);
    hipLaunchKernelGGL(kgen5_kernel, dim3(BATCH * NPIX / TB), dim3(TB), 0, stream,
                       o1buf, wd_red, sd_g, sd_b, sd_m, sd_v, wd_span, k5buf);
    hipLaunchKernelGGL(apply5_kernel, dim3(BATCH * 64 * NPIX / TB), dim3(TB), 0, stream,
                       o1buf, k5buf,
                       bnd_g, bnd_b, bnd_m, bnd_v, prd,
                       bnf_g, bnf_b, bnf_m, bnf_v, prf,
                       out);
}

// Round 3
// 625.305 us; speedup vs baseline: 1.4267x; 1.2322x over previous
//
#include <hip/hip_runtime.h>

#define NPIX 16384   // 128*128
#define BATCH 8

// ---------------- stage-1 kernel generation with fused 2x2 avg-pool
// x (B,32,256,256) -> k1 (B,9,128,128)
__global__ void kgen1_kernel(const float* __restrict__ x,
                             const float* __restrict__ w_red,   // (32,32)
                             const float* __restrict__ g,
                             const float* __restrict__ bta,
                             const float* __restrict__ mn,
                             const float* __restrict__ vr,
                             const float* __restrict__ w_span,  // (9,32)
                             float* __restrict__ kout) {
    int t = blockIdx.x * blockDim.x + threadIdx.x;        // B*NPIX threads
    int b = t >> 14;
    int pix = t & (NPIX - 1);
    int j = pix & 127, i = pix >> 7;
    float inv[32];
    const float* xb = x + ((size_t)b * 32) * 65536 + (size_t)(2 * i) * 256 + 2 * j;
#pragma unroll
    for (int m = 0; m < 32; ++m) {
        const float2* r0 = (const float2*)(xb + (size_t)m * 65536);
        const float2* r1 = (const float2*)(xb + (size_t)m * 65536 + 256);
        float2 a = r0[0], bb = r1[0];
        inv[m] = 0.25f * ((a.x + a.y) + (bb.x + bb.y));
    }
    float kacc[9];
#pragma unroll
    for (int r = 0; r < 9; ++r) kacc[r] = 0.f;
    for (int c = 0; c < 32; ++c) {
        float a0 = 0.f, a1 = 0.f, a2 = 0.f, a3 = 0.f;
#pragma unroll
        for (int m = 0; m < 32; m += 4) {
            a0 = fmaf(w_red[c * 32 + m + 0], inv[m + 0], a0);
            a1 = fmaf(w_red[c * 32 + m + 1], inv[m + 1], a1);
            a2 = fmaf(w_red[c * 32 + m + 2], inv[m + 2], a2);
            a3 = fmaf(w_red[c * 32 + m + 3], inv[m + 3], a3);
        }
        float acc = (a0 + a1) + (a2 + a3);
        float sc = g[c] * rsqrtf(vr[c] + 1e-5f);
        float tt = (acc - mn[c]) * sc + bta[c];
        tt = tt > 0.f ? tt : 0.f;
#pragma unroll
        for (int r = 0; r < 9; ++r) kacc[r] = fmaf(w_span[r * 32 + c], tt, kacc[r]);
    }
    float* ko = kout + ((size_t)b * 9) * NPIX + pix;
#pragma unroll
    for (int r = 0; r < 9; ++r) ko[(size_t)r * NPIX] = kacc[r];
}

// ---------------- stage-1 involution apply (stride 2, pad 1): 4 pixels/thread
// x (B,32,256,256), k1 (B,9,128,128) -> p (B,32,128,128)
__global__ void apply1_kernel(const float* __restrict__ x, const float* __restrict__ kb,
                              float* __restrict__ p) {
    int blk = blockIdx.x;                                 // 16 bpsHi * 32m * 8 bpsLo
    int low3 = blk & 7;
    int m = (blk >> 3) & 31;
    int bps = (blk >> 8) * 8 + low3;                      // b*16+ps; XCD = bps%8
    int b = bps >> 4, ps = bps & 15;
    int pix0 = ps * 1024 + threadIdx.x * 4;
    int i = pix0 >> 7, j0 = pix0 & 127;
    const float* xp = x + ((size_t)(b * 32 + m)) * 65536;
    const float* kp = kb + ((size_t)b * 9) * NPIX + pix0;

    float xw[3][12];
#pragma unroll
    for (int ky = 0; ky < 3; ++ky) {
        int y = 2 * i - 1 + ky;                           // [-1, 255]
        int yc = y < 0 ? 0 : y;
        const float* row = xp + (size_t)yc * 256;
        int co = j0 ? (2 * j0 - 4) : 0;                   // clamp keeps in-buffer
        *(float4*)&xw[ky][0] = *(const float4*)(row + co);
        *(float4*)&xw[ky][4] = *(const float4*)(row + 2 * j0);
        *(float4*)&xw[ky][8] = *(const float4*)(row + 2 * j0 + 4);
    }
    float kv[36];
#pragma unroll
    for (int r = 0; r < 9; ++r) *(float4*)&kv[4 * r] = *(const float4*)(kp + (size_t)r * NPIX);

    float acc[4] = {0.f, 0.f, 0.f, 0.f};
#pragma unroll
    for (int ky = 0; ky < 3; ++ky) {
        int y = 2 * i - 1 + ky;
        bool yok = y >= 0;                                // y<=255 always
#pragma unroll
        for (int kx = 0; kx < 3; ++kx) {
#pragma unroll
            for (int pp = 0; pp < 4; ++pp) {
                // col = 2*(j0+pp)-1+kx; only (pp=0,kx=0,j0=0) can underflow; never overflows
                bool ok = yok && !(kx == 0 && pp == 0 && j0 == 0);
                int widx = 3 + 2 * pp + kx;               // into [2j0-4 .. 2j0+8)
                float xv = ok ? xw[ky][widx] : 0.f;
                acc[pp] = fmaf(xv, kv[4 * (3 * ky + kx) + pp], acc[pp]);
            }
        }
    }
    float4 o; float* op = (float*)&o;
#pragma unroll
    for (int pp = 0; pp < 4; ++pp) op[pp] = acc[pp];
    *(float4*)(p + ((size_t)(b * 32 + m)) * NPIX + pix0) = o;
}

// ---------------- 1x1 conv 32->64 + bn(1e-3) + prelu : p -> o1, 4 pixels/thread
__global__ void conv1_kernel(const float* __restrict__ p, const float* __restrict__ w,  // (64,32)
                             const float* __restrict__ g, const float* __restrict__ bt,
                             const float* __restrict__ mn, const float* __restrict__ vr,
                             const float* __restrict__ pr, float* __restrict__ o1) {
    int blk = blockIdx.x;                                 // 16 bpsHi * 64c * 8 bpsLo
    int low3 = blk & 7;
    int c = (blk >> 3) & 63;
    int bps = (blk >> 9) * 8 + low3;
    int b = bps >> 4, ps = bps & 15;
    int pix0 = ps * 1024 + threadIdx.x * 4;
    const float* pp = p + ((size_t)b * 32) * NPIX + pix0;
    float a0[4] = {0.f,0.f,0.f,0.f}, a1[4] = {0.f,0.f,0.f,0.f};
#pragma unroll
    for (int m = 0; m < 32; m += 2) {
        float4 v0 = *(const float4*)(pp + (size_t)m * NPIX);
        float4 v1 = *(const float4*)(pp + (size_t)(m + 1) * NPIX);
        float w0 = w[c * 32 + m], w1 = w[c * 32 + m + 1];
        a0[0] = fmaf(w0, v0.x, a0[0]); a0[1] = fmaf(w0, v0.y, a0[1]);
        a0[2] = fmaf(w0, v0.z, a0[2]); a0[3] = fmaf(w0, v0.w, a0[3]);
        a1[0] = fmaf(w1, v1.x, a1[0]); a1[1] = fmaf(w1, v1.y, a1[1]);
        a1[2] = fmaf(w1, v1.z, a1[2]); a1[3] = fmaf(w1, v1.w, a1[3]);
    }
    float sc = g[c] * rsqrtf(vr[c] + 1e-3f);
    float4 o; float* op = (float*)&o;
#pragma unroll
    for (int q = 0; q < 4; ++q) {
        float v = ((a0[q] + a1[q]) - mn[c]) * sc + bt[c];
        v = v > 0.f ? v : pr[c] * v;
        op[q] = v;
    }
    *(float4*)(o1 + ((size_t)(b * 64 + c)) * NPIX + pix0) = o;
}

// ---------------- kernel-gen for dilated stages, one stage per block
// o1 (B,64,128,128) -> k5 (5,B,9,128,128)
__global__ void kgen5_kernel(const float* __restrict__ o1,
                             const float* __restrict__ wred5,   // (5,64,64)
                             const float* __restrict__ sg5, const float* __restrict__ sb5,
                             const float* __restrict__ sm5, const float* __restrict__ sv5,
                             const float* __restrict__ wspan5,  // (5,9,64)
                             float* __restrict__ kout) {
    int blk = blockIdx.x;                                 // (P>>3)*40 + s*8 + (P&7); XCD = P%8
    int q = blk >> 3;
    int s = q % 5;
    int P = (q / 5) * 8 + (blk & 7);                      // [0,512)
    int gp = P * 256 + threadIdx.x;                       // global pixel id
    int b = gp >> 14;
    int pix = gp & (NPIX - 1);
    float inv[64];
    const float* base = o1 + ((size_t)b * 64) * NPIX + pix;
#pragma unroll
    for (int m = 0; m < 64; ++m) inv[m] = base[(size_t)m * NPIX];
    const float* wr = wred5 + s * 4096;
    const float* wsp = wspan5 + s * 576;
    const float* g = sg5 + s * 64;  const float* bt = sb5 + s * 64;
    const float* mn = sm5 + s * 64; const float* vr = sv5 + s * 64;
    float kacc[9];
#pragma unroll
    for (int r = 0; r < 9; ++r) kacc[r] = 0.f;
    for (int c = 0; c < 64; ++c) {
        float a0 = 0.f, a1 = 0.f, a2 = 0.f, a3 = 0.f;
#pragma unroll
        for (int m = 0; m < 64; m += 4) {
            a0 = fmaf(wr[c * 64 + m + 0], inv[m + 0], a0);
            a1 = fmaf(wr[c * 64 + m + 1], inv[m + 1], a1);
            a2 = fmaf(wr[c * 64 + m + 2], inv[m + 2], a2);
            a3 = fmaf(wr[c * 64 + m + 3], inv[m + 3], a3);
        }
        float acc = (a0 + a1) + (a2 + a3);
        float sc = g[c] * rsqrtf(vr[c] + 1e-5f);
        float tt = (acc - mn[c]) * sc + bt[c];
        tt = tt > 0.f ? tt : 0.f;
#pragma unroll
        for (int r = 0; r < 9; ++r) kacc[r] = fmaf(wsp[r * 64 + c], tt, kacc[r]);
    }
    float* ko = kout + ((size_t)(s * BATCH + b) * 9) * NPIX + pix;
#pragma unroll
    for (int r = 0; r < 9; ++r) ko[(size_t)r * NPIX] = kacc[r];
}

// ---------------- fused dilated involution: one stage's 4-pixel tile
template <int DIL>
__device__ __forceinline__ void invo_tap4(const float* __restrict__ xp,
                                          const float* __restrict__ kp,
                                          int i, int j0, float acc[4]) {
    constexpr int LOFF = (DIL < 4) ? 4 : DIL;
    float xw[3][12];
#pragma unroll
    for (int ky = 0; ky < 3; ++ky) {
        int y = i + DIL * (ky - 1);
        int yc = ((unsigned)y < 128u) ? y : i;            // safe row for OOB (zeroed later)
        const float* row = xp + (size_t)yc * 128;
        *(float4*)&xw[ky][0] = *(const float4*)(row + j0 - LOFF);  // guard offset covers underflow
        *(float4*)&xw[ky][4] = *(const float4*)(row + j0);
        *(float4*)&xw[ky][8] = *(const float4*)(row + j0 + LOFF);
    }
    float kv[36];
#pragma unroll
    for (int r = 0; r < 9; ++r) *(float4*)&kv[4 * r] = *(const float4*)(kp + (size_t)r * NPIX);
#pragma unroll
    for (int ky = 0; ky < 3; ++ky) {
        int y = i + DIL * (ky - 1);
        bool yok = (unsigned)y < 128u;
#pragma unroll
        for (int kx = 0; kx < 3; ++kx) {
#pragma unroll
            for (int pp = 0; pp < 4; ++pp) {
                int xx = j0 + pp + DIL * (kx - 1);
                bool ok = yok && ((kx == 1) || ((unsigned)xx < 128u));
                int widx = 4 + pp + ((DIL < 4) ? DIL : 4) * (kx - 1);
                float xv = ok ? xw[ky][widx] : 0.f;
                acc[pp] = fmaf(xv, kv[4 * (3 * ky + kx) + pp], acc[pp]);
            }
        }
    }
}

__global__ void apply5_kernel(const float* __restrict__ o1, const float* __restrict__ kb, // (5,B,9,NPIX)
                              const float* __restrict__ gd5, const float* __restrict__ bd5,
                              const float* __restrict__ md5, const float* __restrict__ vd5,
                              const float* __restrict__ ad5,
                              const float* __restrict__ gf, const float* __restrict__ bf,
                              const float* __restrict__ mf, const float* __restrict__ vf,
                              const float* __restrict__ af,
                              float* __restrict__ out) {
    int blk = blockIdx.x;                                 // 16 bpsHi * 64c * 8 bpsLo
    int low3 = blk & 7;
    int c = (blk >> 3) & 63;
    int bps = (blk >> 9) * 8 + low3;
    int b = bps >> 4, ps = bps & 15;
    int pix0 = ps * 1024 + threadIdx.x * 4;
    int i = pix0 >> 7, j0 = pix0 & 127;
    const float* xp = o1 + ((size_t)(b * 64 + c)) * NPIX;

#define STAGE(S, D)                                                            \
    {                                                                          \
        float acc[4] = {0.f, 0.f, 0.f, 0.f};                                   \
        const float* kp = kb + ((size_t)(S * BATCH + b) * 9) * NPIX + pix0;    \
        invo_tap4<D>(xp, kp, i, j0, acc);                                      \
        int sc = S * 64 + c;                                                   \
        float scd = gd5[sc] * rsqrtf(vd5[sc] + 1e-3f);                         \
        float scf = gf[sc] * rsqrtf(vf[sc] + 1e-3f);                           \
        float4 o; float* op = (float*)&o;                                      \
        _Pragma("unroll")                                                      \
        for (int pp = 0; pp < 4; ++pp) {                                       \
            float v = (acc[pp] - md5[sc]) * scd + bd5[sc];                     \
            v = v > 0.f ? v : ad5[sc] * v;                                     \
            v = (v - mf[sc]) * scf + bf[sc];                                   \
            v = v > 0.f ? v : af[sc] * v;                                      \
            op[pp] = v;                                                        \
        }                                                                      \
        *(float4*)(out + ((size_t)(b * 320 + sc)) * NPIX + pix0) = o;          \
    }
    STAGE(0, 1)
    STAGE(1, 2)
    STAGE(2, 4)
    STAGE(3, 8)
    STAGE(4, 16)
#undef STAGE
}

extern "C" void kernel_launch(void* const* d_in, const int* in_sizes, int n_in,
                              void* d_out, int out_size, void* d_ws, size_t ws_size,
                              hipStream_t stream) {
    const float* x       = (const float*)d_in[0];
    const float* w1_init = (const float*)d_in[1];
    const float* w1_red  = (const float*)d_in[2];
    const float* s1_g    = (const float*)d_in[3];
    const float* s1_b    = (const float*)d_in[4];
    const float* s1_m    = (const float*)d_in[5];
    const float* s1_v    = (const float*)d_in[6];
    const float* w1_span = (const float*)d_in[7];
    const float* bn1_g   = (const float*)d_in[8];
    const float* bn1_b   = (const float*)d_in[9];
    const float* bn1_m   = (const float*)d_in[10];
    const float* bn1_v   = (const float*)d_in[11];
    const float* pr1     = (const float*)d_in[12];
    const float* wd_red  = (const float*)d_in[13];  // (5,64,64)
    const float* sd_g    = (const float*)d_in[14];
    const float* sd_b    = (const float*)d_in[15];
    const float* sd_m    = (const float*)d_in[16];
    const float* sd_v    = (const float*)d_in[17];
    const float* wd_span = (const float*)d_in[18];  // (5,9,64)
    const float* bnd_g   = (const float*)d_in[19];
    const float* bnd_b   = (const float*)d_in[20];
    const float* bnd_m   = (const float*)d_in[21];
    const float* bnd_v   = (const float*)d_in[22];
    const float* prd     = (const float*)d_in[23];
    const float* bnf_g   = (const float*)d_in[24];
    const float* bnf_b   = (const float*)d_in[25];
    const float* bnf_m   = (const float*)d_in[26];
    const float* bnf_v   = (const float*)d_in[27];
    const float* prf     = (const float*)d_in[28];
    float* out = (float*)d_out;

    float* ws    = (float*)d_ws;
    float* o1buf = ws + 64;                    // +64 guard floats for j0-LOFF underflow
    float* k1buf = o1buf + 8388608;            // 8*64*16384
    float* k5buf = k1buf + 1179648;            // 8*9*16384
    float* pbuf  = k5buf + 5898240;            // 5*8*9*16384; pbuf = 8*32*16384

    const int TB = 256;

    hipLaunchKernelGGL(kgen1_kernel, dim3(BATCH * NPIX / TB), dim3(TB), 0, stream,
                       x, w1_red, s1_g, s1_b, s1_m, s1_v, w1_span, k1buf);
    hipLaunchKernelGGL(apply1_kernel, dim3(4096), dim3(TB), 0, stream,
                       x, k1buf, pbuf);
    hipLaunchKernelGGL(conv1_kernel, dim3(8192), dim3(TB), 0, stream,
                       pbuf, w1_init, bn1_g, bn1_b, bn1_m, bn1_v, pr1, o1buf);
    hipLaunchKernelGGL(kgen5_kernel, dim3(2560), dim3(TB), 0, stream,
                       o1buf, wd_red, sd_g, sd_b, sd_m, sd_v, wd_span, k5buf);
    hipLaunchKernelGGL(apply5_kernel, dim3(8192), dim3(TB), 0, stream,
                       o1buf, k5buf,
                       bnd_g, bnd_b, bnd_m, bnd_v, prd,
                       bnf_g, bnf_b, bnf_m, bnf_v, prf,
                       out);
}